// Round 1
// baseline (47.226 us; speedup 1.0000x reference)
//
#include <hip/hip_runtime.h>
#include <stdint.h>

#define NROWS 8192
#define NDIM 128
#define NB 64                     // 8192/128 row-blocks
#define NBLOCKS (NB * (NB + 1) / 2)  // 2080 lower-triangular blocks

typedef short s16x8 __attribute__((ext_vector_type(8)));
typedef float f32x4 __attribute__((ext_vector_type(4)));
typedef __attribute__((address_space(3))) uint32_t lds_u32_t;
typedef __attribute__((address_space(1))) const uint32_t glb_u32_t;

__device__ __forceinline__ uint32_t f32_to_bf16_rne(float x) {
    uint32_t u = __float_as_uint(x);
    return (u + 0x7FFFu + ((u >> 16) & 1u)) >> 16;
}

// One wave per row: f32 load, L2-norm via shfl reduce, bf16 store (packed u32).
__global__ __launch_bounds__(256) void normalize_kernel(const float* __restrict__ feat,
                                                        uint32_t* __restrict__ fhat) {
    int wave = threadIdx.x >> 6;
    int lane = threadIdx.x & 63;
    int row = blockIdx.x * 4 + wave;
    const float2* src = reinterpret_cast<const float2*>(feat) + row * 64 + lane;
    float2 v = *src;
    float ss = v.x * v.x + v.y * v.y;
#pragma unroll
    for (int off = 32; off; off >>= 1) ss += __shfl_xor(ss, off);
    float norm = fmaxf(sqrtf(ss), 1e-12f);
    float sc = 1.0f / norm;
    fhat[row * 64 + lane] = (f32_to_bf16_rne(v.y * sc) << 16) | f32_to_bf16_rne(v.x * sc);
}

// Zero the output accumulator; detect whether labels arrived as int64
// (values 0..99 -> all high 32-bit words zero) or int32.
__global__ void prep_kernel(const int* __restrict__ labels, float* __restrict__ out,
                            int* __restrict__ flag) {
    if (threadIdx.x == 0) {
        out[0] = 0.0f;
        int is64 = 1;
        for (int i = 0; i < 64; ++i)
            if (labels[2 * i + 1] != 0) { is64 = 0; break; }
        flag[0] = is64;
    }
}

// One 128x128 tile of S = F̂ F̂^T per block (lower triangle only), fused mask+relu+reduce.
__global__ __launch_bounds__(256, 2) void shadow_gemm(const uint32_t* __restrict__ fhat,
                                                      const int* __restrict__ labels,
                                                      const int* __restrict__ flag,
                                                      float* __restrict__ out) {
    __shared__ __align__(16) char sm[65536];  // A tile [0,32K), B tile [32K,64K)

    // triangular block decode: t -> (bi, bj), bi >= bj
    int t = blockIdx.x;
    int bi = (int)((sqrtf(8.0f * (float)t + 1.0f) - 1.0f) * 0.5f);
    while ((bi + 1) * (bi + 2) / 2 <= t) ++bi;
    while (bi * (bi + 1) / 2 > t) --bi;
    int bj = t - bi * (bi + 1) / 2;

    int tid = threadIdx.x;
    int lane = tid & 63;
    int wave = tid >> 6;

    // Stage A (rows of block bi) and B (rows of block bj), full K=128, once.
    // LDS dest is LINEAR (global_load_lds requirement); the XOR swizzle
    // (byte ^= (row&7)<<4) is applied by permuting the GLOBAL source chunks
    // (rule #21: inverse-swizzled source + swizzled read).
    {
        int r16 = tid >> 4;                  // row within 16-row slab
        uint32_t cst = (uint32_t)((tid & 15) << 4);  // stored 16B chunk
#pragma unroll
        for (int it = 0; it < 8; ++it) {
            int row = it * 16 + r16;
            uint32_t csrc = cst ^ (uint32_t)((row & 7) << 4);
            const char* gA = (const char*)fhat + ((bi * 128 + row) * 256 + csrc);
            const char* gB = (const char*)fhat + ((bj * 128 + row) * 256 + csrc);
            uint32_t l = (uint32_t)(it * 4096 + tid * 16);
            __builtin_amdgcn_global_load_lds((glb_u32_t*)gA, (lds_u32_t*)(sm + l), 16, 0, 0);
            __builtin_amdgcn_global_load_lds((glb_u32_t*)gB, (lds_u32_t*)(sm + 32768 + l), 16, 0, 0);
        }
    }
    __syncthreads();

    int wm = wave >> 1, wn = wave & 1;       // 2x2 wave grid, 64x64 per wave
    int rbase = lane & 15;
    uint32_t kcol = (uint32_t)((lane >> 4) << 4);  // byte offset of lane's 8-elem k-group

    f32x4 acc[4][4];
#pragma unroll
    for (int mi = 0; mi < 4; ++mi)
#pragma unroll
        for (int ni = 0; ni < 4; ++ni) acc[mi][ni] = f32x4{0.f, 0.f, 0.f, 0.f};

#pragma unroll
    for (int ks = 0; ks < 4; ++ks) {         // 4 K-steps of 32
        uint32_t c2 = (uint32_t)(ks * 64) + kcol;
        s16x8 a[4], b[4];
#pragma unroll
        for (int mi = 0; mi < 4; ++mi) {
            int r = wm * 64 + mi * 16 + rbase;
            uint32_t ad = (uint32_t)(r * 256) + (c2 ^ (uint32_t)((r & 7) << 4));
            a[mi] = *reinterpret_cast<const s16x8*>(sm + ad);
        }
#pragma unroll
        for (int ni = 0; ni < 4; ++ni) {
            int r = wn * 64 + ni * 16 + rbase;
            uint32_t ad = (uint32_t)(r * 256) + (c2 ^ (uint32_t)((r & 7) << 4));
            b[ni] = *reinterpret_cast<const s16x8*>(sm + 32768 + ad);
        }
#pragma unroll
        for (int mi = 0; mi < 4; ++mi)
#pragma unroll
            for (int ni = 0; ni < 4; ++ni)
                acc[mi][ni] = __builtin_amdgcn_mfma_f32_16x16x32_bf16(a[mi], b[ni],
                                                                      acc[mi][ni], 0, 0, 0);
    }

    // Epilogue: per-element mask + relu, reduce to scalar.
    int shl = flag[0];  // 1 if labels are int64 (stride-2 int32 view), else 0
    int labr[16];
#pragma unroll
    for (int mi = 0; mi < 4; ++mi)
#pragma unroll
        for (int rr = 0; rr < 4; ++rr) {
            int gi = bi * 128 + wm * 64 + mi * 16 + ((lane >> 4) << 2) + rr;
            labr[mi * 4 + rr] = labels[gi << shl];
        }

    float lsum = 0.0f;
#pragma unroll
    for (int ni = 0; ni < 4; ++ni) {
        int c = wn * 64 + ni * 16 + rbase;
        int gj = bj * 128 + c;
        int labj = labels[gj << shl];
#pragma unroll
        for (int mi = 0; mi < 4; ++mi) {
#pragma unroll
            for (int rr = 0; rr < 4; ++rr) {
                int gi = bi * 128 + wm * 64 + mi * 16 + ((lane >> 4) << 2) + rr;
                float s = acc[mi][ni][rr];
                // pos: relu(10s-9); neg: relu(11-10s)
                float v = (labr[mi * 4 + rr] == labj)
                              ? fmaxf(fmaf(10.0f, s, -9.0f), 0.0f)
                              : fmaxf(fmaf(-10.0f, s, 11.0f), 0.0f);
                lsum += (gi != gj) ? v : 0.0f;   // exclude diagonal
            }
        }
    }
    float wgt = (bi == bj) ? 1.0f : 2.0f;        // off-diag tiles cover (i,j) and (j,i)
    lsum *= wgt * (1.0f / 67100672.0f);          // 8192*8191 exact in f32

#pragma unroll
    for (int off = 32; off; off >>= 1) lsum += __shfl_xor(lsum, off);
    __syncthreads();                             // tiles dead; reuse LDS for reduction
    float* red = reinterpret_cast<float*>(sm);
    if (lane == 0) red[wave] = lsum;
    __syncthreads();
    if (tid == 0) atomicAdd(out, red[0] + red[1] + red[2] + red[3]);
}

extern "C" void kernel_launch(void* const* d_in, const int* in_sizes, int n_in,
                              void* d_out, int out_size, void* d_ws, size_t ws_size,
                              hipStream_t stream) {
    const float* feat = (const float*)d_in[0];
    const int* labels = (const int*)d_in[1];
    float* out = (float*)d_out;
    uint32_t* fhat = (uint32_t*)d_ws;                       // 8192*128 bf16 = 2 MB
    int* flag = (int*)((char*)d_ws + (size_t)NROWS * NDIM * 2);

    prep_kernel<<<1, 64, 0, stream>>>(labels, out, flag);
    normalize_kernel<<<NROWS / 4, 256, 0, stream>>>(feat, fhat);
    shadow_gemm<<<NBLOCKS, 256, 0, stream>>>(fhat, labels, flag, out);
}